// Round 11
// baseline (873.827 us; speedup 1.0000x reference)
//
#include <hip/hip_runtime.h>
#include <hip/hip_bf16.h>
#include <cstdint>

typedef unsigned short u16;
typedef __attribute__((ext_vector_type(8))) _Float16 f16x8;
typedef __attribute__((ext_vector_type(4))) float f32x4;
typedef __attribute__((ext_vector_type(8))) unsigned short u16x8;

typedef const __attribute__((address_space(1))) void* gas1p;
typedef __attribute__((address_space(3))) void* las3p;
typedef const __attribute__((address_space(3))) u16* lc16p;

__device__ __forceinline__ void gld_lds16(const void* g, void* l) {
    __builtin_amdgcn_global_load_lds((gas1p)g, (las3p)l, 16, 0, 0);
}

// offset-folded asm ds_read_b128 (1 base VGPR + imm offsets; clobber-free)
template<int OFF>
__device__ __forceinline__ f16x8 dsr128o(const u16* p) {
    f16x8 r;
    asm volatile("ds_read_b128 %0, %1 offset:%2" : "=v"(r) : "v"((lc16p)p), "i"(OFF));
    return r;
}

__device__ __forceinline__ u16 f2h(float f) {
    _Float16 h = (_Float16)f;
    return __builtin_bit_cast(u16, h);
}

// ---------------- prep: x fp32 -> fp16 ----------------
__global__ void cvt_x_kernel(const float4* __restrict__ x, u16* __restrict__ xb) {
    size_t i = (size_t)blockIdx.x * blockDim.x + threadIdx.x;
    float4 a = x[2 * i];
    float4 b = x[2 * i + 1];
    u16x8 o;
    o[0] = f2h(a.x); o[1] = f2h(a.y); o[2] = f2h(a.z); o[3] = f2h(a.w);
    o[4] = f2h(b.x); o[5] = f2h(b.y); o[6] = f2h(b.z); o[7] = f2h(b.w);
    *(u16x8*)&xb[i * 8] = o;
}

// ---------------- prep: weight norm, all 5 layers in 2 launches ----------------
struct WnDesc {
    const float* v; const float* g; u16* wT; float* partial;
    int K; int N; int blk0;
};
struct WnPack { WnDesc d[5]; int nlayer; };

__global__ void wn_partial_all(WnPack p) {
    int b = blockIdx.x;
    int l = 0;
    while (l + 1 < p.nlayer && b >= p.d[l + 1].blk0) l++;
    const WnDesc& d = p.d[l];
    int lb = b - d.blk0;
    int nbx = d.N >> 6;
    int bx = lb % nbx, seg = lb / nbx;

    int lane = threadIdx.x & 63;
    int tr = threadIdx.x >> 6;
    int n = bx * 64 + lane;
    int kseg = d.K >> 3;
    int kbeg = seg * kseg;
    float s = 0.f;
    for (int k = kbeg + tr; k < kbeg + kseg; k += 4) {
        float x = d.v[(size_t)k * d.N + n];
        s += x * x;
    }
    __shared__ float red[4][64];
    red[tr][lane] = s;
    __syncthreads();
    if (tr == 0)
        d.partial[seg * d.N + n] = red[0][lane] + red[1][lane] + red[2][lane] + red[3][lane];
}

__global__ void wn_write_all(WnPack p) {
    int b = blockIdx.x;
    int l = 0;
    while (l + 1 < p.nlayer && b >= p.d[l + 1].blk0) l++;
    const WnDesc& d = p.d[l];
    int lb = b - d.blk0;
    int nbx = d.N >> 6;
    int bx = lb % nbx, seg = lb / nbx;

    int lane = threadIdx.x & 63;
    int tr = threadIdx.x >> 6;
    int n = bx * 64 + lane;
    float s = 0.f;
#pragma unroll
    for (int i = 0; i < 8; i++) s += d.partial[i * d.N + n];
    float sc = d.g[n] / sqrtf(s);

    int kseg = d.K >> 3;
    int kbeg = seg * kseg;
    for (int k = kbeg + tr; k < kbeg + kseg; k += 4)
        d.wT[(size_t)n * d.K + k] = f2h(d.v[(size_t)k * d.N + n] * sc);
}

// ---------------- main GEMM: 256x256, BK=64, 8 waves, A-via-LDS + B-from-L2 ----
// B (2 MB, chip-hot) is loaded per-wave straight from global (L2) into regs,
// one tile ahead; LDS stages A only (64 KB total, 4 gld_lds/tile, 1 barrier).
// In-order vmcnt ledger (issue order per steady tile t):
//   ... [stA(t+1) x4] ... [B0(t+1) x4] [B1(t+1) x4]   (B(t) issued in t-1)
//   mm00 waits B0(t): all older -> free.  mm01 waits B1(t): forces B1(t) only,
//   SPARES stA(t+1) (newer).  End-of-tile VMC(8): outstanding =
//   stA(t+1)+B0(t+1)+B1(t+1)=12 -> forces stA(t+1) (issued ~2800 cyc ago, free).
//   BAR gates the buffer flip (WAR: prior reads all lgkm(0)-drained).
// A-reads split LGKM(8)/LGKM(0): rA1's 8 reads hide under mm00/mm01.
template<int N, int K, bool ACT, bool OUTF32>
__global__ __launch_bounds__(512, 2) void gemm_bl2(
    const u16* __restrict__ A, const u16* __restrict__ Bt,
    u16* __restrict__ Ch, float* __restrict__ Cf)
{
    constexpr int M = 65536;
    constexpr int NT = K / 64;
    constexpr int NTN = N / 256;
    constexpr int NWG = (M / 256) * NTN;

    __shared__ u16 sA[2][256 * 64];   // 64 KB

    const int bid = blockIdx.x;
    const int wk = (bid & 7) * (NWG >> 3) + (bid >> 3);   // bijective: NWG%8==0
    const int tm = wk / NTN, tn = wk % NTN;
    const long m0 = (long)tm * 256;
    const int n0 = tn * 256;

    const int tid = threadIdx.x;
    const int lane = tid & 63;
    const int wid = tid >> 6;
    const int wm = (wid >> 2) * 128;
    const int wn = (wid & 3) * 64;

    // ---- A staging (inverse-swizzled source, linear LDS dest) ----
    const int r8 = tid >> 3;
    const int gcol = ((tid & 7) ^ (r8 & 7)) * 8;
    const u16* Abase = A + (m0 + r8) * (size_t)K + gcol;
    const int dst8 = tid * 8;
    auto stA = [&](int buf, int t) {
        gld_lds16(Abase + (size_t)t * 64, &sA[buf][dst8]);
        gld_lds16(Abase + (size_t)128 * K + (size_t)t * 64, &sA[buf][2 * 4096 + dst8]);
        gld_lds16(Abase + (size_t)64 * K + (size_t)t * 64, &sA[buf][1 * 4096 + dst8]);
        gld_lds16(Abase + (size_t)192 * K + (size_t)t * 64, &sA[buf][3 * 4096 + dst8]);
    };

    // ---- A fragment reads (swizzled, offset-folded) ----
    const int rbase = lane & 15;
    const int co0 = ((lane >> 4) ^ (lane & 7)) * 8;
    const int arow0 = (wm + rbase) * 64 + co0;

    // ---- B direct-from-global fragment loads ----
    const int bn = n0 + wn + (lane & 15);
    const int bk = (lane >> 4) * 8;
    auto ldBg = [&](f16x8 (&dst)[2][2], int qn, int t) {
#pragma unroll
        for (int j2 = 0; j2 < 2; j2++)
#pragma unroll
            for (int kk = 0; kk < 2; kk++)
                dst[j2][kk] = *(const f16x8*)&Bt[
                    (size_t)(bn + qn * 32 + j2 * 16) * K + t * 64 + kk * 32 + bk];
    };

    f32x4 acc[8][4] = {};
    f16x8 rA0[4][2], rA1[4][2], B0[2][2], B1[2][2];

    auto mmq = [&](f16x8 (&ra)[4][2], f16x8 (&rb)[2][2], int qm, int qn) {
        __builtin_amdgcn_s_setprio(1);
#pragma unroll
        for (int kk = 0; kk < 2; kk++)
#pragma unroll
            for (int i = 0; i < 4; i++)
#pragma unroll
                for (int j2 = 0; j2 < 2; j2++)
                    acc[qm * 4 + i][qn * 2 + j2] = __builtin_amdgcn_mfma_f32_16x16x32_f16(
                        ra[i][kk], rb[j2][kk], acc[qm * 4 + i][qn * 2 + j2], 0, 0, 0);
        __builtin_amdgcn_s_setprio(0);
    };
    auto BAR = [&]() { __builtin_amdgcn_s_barrier(); };
#define LGKM(n) { asm volatile("s_waitcnt lgkmcnt(" #n ")"); __builtin_amdgcn_sched_barrier(0); }
#define VMC(n)  { asm volatile("s_waitcnt vmcnt(" #n ")");  __builtin_amdgcn_sched_barrier(0); }

    // ---- prologue: stage A(0); issue B(0); force stages only ----
    stA(0, 0);
    ldBg(B0, 0, 0);
    ldBg(B1, 1, 0);
    VMC(8);           // 12 outstanding -> forces stA(0) (oldest 4)
    BAR();

    // ---- main loop ----
    for (int t = 0; t < NT; t++) {
        const int cur = t & 1, nxt = cur ^ 1;
        const bool more = (t + 1 < NT);

        // A reads for this tile (16 asm ds_read_b128, offset-folded)
        const u16* pA0 = &sA[cur][arow0];
        const u16* pA1 = &sA[cur][arow0 ^ 32];
#pragma unroll
        for (int i = 0; i < 4; i++) {
            // qm0: rows i*16 -> byte offset i*2048 ; qm1: +64 rows -> +8192
            if (i == 0) { rA0[0][0] = dsr128o<0>(pA0);     rA0[0][1] = dsr128o<0>(pA1); }
            if (i == 1) { rA0[1][0] = dsr128o<2048>(pA0);  rA0[1][1] = dsr128o<2048>(pA1); }
            if (i == 2) { rA0[2][0] = dsr128o<4096>(pA0);  rA0[2][1] = dsr128o<4096>(pA1); }
            if (i == 3) { rA0[3][0] = dsr128o<6144>(pA0);  rA0[3][1] = dsr128o<6144>(pA1); }
        }
#pragma unroll
        for (int i = 0; i < 4; i++) {
            if (i == 0) { rA1[0][0] = dsr128o<8192>(pA0);  rA1[0][1] = dsr128o<8192>(pA1); }
            if (i == 1) { rA1[1][0] = dsr128o<10240>(pA0); rA1[1][1] = dsr128o<10240>(pA1); }
            if (i == 2) { rA1[2][0] = dsr128o<12288>(pA0); rA1[2][1] = dsr128o<12288>(pA1); }
            if (i == 3) { rA1[3][0] = dsr128o<14336>(pA0); rA1[3][1] = dsr128o<14336>(pA1); }
        }
        if (more) stA(nxt, t + 1);       // 4 gld_lds (newest VMEM)

        LGKM(8);                          // rA0 ready; rA1 in flight under MFMAs
        mmq(rA0, B0, 0, 0);               // compiler wait for B0(t): all-old, free
        mmq(rA0, B1, 0, 1);               // wait B1(t): spares stA(t+1) (newer)
        LGKM(0);                          // rA1 ready
        mmq(rA1, B0, 1, 0);
        if (more) ldBg(B0, 0, t + 1);     // B0 regs dead after mm10 -> reissue
        mmq(rA1, B1, 1, 1);
        if (more) {
            ldBg(B1, 1, t + 1);           // B1 regs dead after mm11 -> reissue
            VMC(8);                       // forces stA(t+1); spares B(t+1)
            BAR();                        // buffer flip
        }
    }
#undef LGKM
#undef VMC

    // ---- epilogue: C layout col = lane&15, row = (lane>>4)*4 + reg ----
    const long crow0 = m0 + wm + ((lane >> 4) << 2);
    const int ccol0 = n0 + wn + (lane & 15);
#pragma unroll
    for (int fi = 0; fi < 8; fi++) {
#pragma unroll
        for (int r = 0; r < 4; r++) {
            const size_t rowoff = (size_t)(crow0 + fi * 16 + r) * N;
#pragma unroll
            for (int fj = 0; fj < 4; fj++) {
                float v = acc[fi][fj][r];
                if (ACT) v = fmaxf(v, 0.f) + __logf(1.f + __expf(-fabsf(v)));
                if (OUTF32) Cf[rowoff + ccol0 + fj * 16] = v;
                else        Ch[rowoff + ccol0 + fj * 16] = f2h(v);
            }
        }
    }
}

// ---------------- launch ----------------
extern "C" void kernel_launch(void* const* d_in, const int* in_sizes, int n_in,
                              void* d_out, int out_size, void* d_ws, size_t ws_size,
                              hipStream_t stream) {
    const float* x  = (const float*)d_in[0];
    const float* v1 = (const float*)d_in[1];
    const float* g1 = (const float*)d_in[2];
    const float* v2 = (const float*)d_in[3];
    const float* g2 = (const float*)d_in[4];
    const float* v3 = (const float*)d_in[5];
    const float* g3 = (const float*)d_in[6];
    const float* v4 = (const float*)d_in[7];
    const float* g4 = (const float*)d_in[8];
    const float* v5 = (const float*)d_in[9];
    const float* g5 = (const float*)d_in[10];
    float* out = (float*)d_out;

    const int M = 65536;
    char* ws = (char*)d_ws;
    u16* bufA = (u16*)(ws);                          // 128 MB
    u16* bufB = (u16*)(ws + 0x8000000ULL);           // 128 MB
    u16* w1T  = (u16*)(ws + 0x10000000ULL);
    u16* w2T  = w1T + 1024 * 512;
    u16* w3T  = w2T + 1024 * 1024;
    u16* w4T  = w3T + 1024 * 1024;
    u16* w5T  = w4T + 1024 * 1024;
    float* part = (float*)(ws + 0x10800000ULL);      // 5 x 8 x 1024 f32

    cvt_x_kernel<<<(M * 512) / (256 * 8), 256, 0, stream>>>((const float4*)x, bufB);

    WnPack pk;
    int cum = 0;
    auto mk = [&](int i, const float* v, const float* g, u16* wT, int K, int N) {
        pk.d[i] = WnDesc{v, g, wT, part + i * 8 * 1024, K, N, cum};
        cum += (N / 64) * 8;
    };
    mk(0, v1, g1, w1T, 512, 1024);
    mk(1, v2, g2, w2T, 1024, 1024);
    mk(2, v3, g3, w3T, 1024, 1024);
    mk(3, v4, g4, w4T, 1024, 1024);
    mk(4, v5, g5, w5T, 1024, 512);
    pk.nlayer = 5;

    wn_partial_all<<<cum, 256, 0, stream>>>(pk);
    wn_write_all<<<cum, 256, 0, stream>>>(pk);

    gemm_bl2<1024, 512,  true,  false><<<1024, 512, 0, stream>>>(bufB, w1T, bufA, nullptr);
    gemm_bl2<1024, 1024, true,  false><<<1024, 512, 0, stream>>>(bufA, w2T, bufB, nullptr);
    gemm_bl2<1024, 1024, true,  false><<<1024, 512, 0, stream>>>(bufB, w3T, bufA, nullptr);
    gemm_bl2<1024, 1024, true,  false><<<1024, 512, 0, stream>>>(bufA, w4T, bufB, nullptr);
    gemm_bl2<512,  1024, false, true ><<<512,  512, 0, stream>>>(bufB, w5T, nullptr, out);

    (void)in_sizes; (void)n_in; (void)out_size; (void)ws_size;
}

// Round 12
// 755.297 us; speedup vs baseline: 1.1569x; 1.1569x over previous
//
#include <hip/hip_runtime.h>
#include <hip/hip_bf16.h>
#include <cstdint>

typedef unsigned short u16;
typedef __attribute__((ext_vector_type(8))) _Float16 f16x8;
typedef __attribute__((ext_vector_type(4))) float f32x4;
typedef __attribute__((ext_vector_type(8))) unsigned short u16x8;

typedef const __attribute__((address_space(1))) void* gas1p;
typedef __attribute__((address_space(3))) void* las3p;
typedef const __attribute__((address_space(3))) u16* lc16p;

__device__ __forceinline__ void gld_lds16(const void* g, void* l) {
    __builtin_amdgcn_global_load_lds((gas1p)g, (las3p)l, 16, 0, 0);
}

// clobber-free asm ds_read_b128 with byte-immediate offset
template<int OFF>
__device__ __forceinline__ f16x8 dsr128o(const u16* p) {
    f16x8 r;
    asm volatile("ds_read_b128 %0, %1 offset:%2" : "=v"(r) : "v"((lc16p)p), "i"(OFF));
    return r;
}

__device__ __forceinline__ u16 f2h(float f) {
    _Float16 h = (_Float16)f;
    return __builtin_bit_cast(u16, h);
}

// ---------------- prep: x fp32 -> fp16 ----------------
__global__ void cvt_x_kernel(const float4* __restrict__ x, u16* __restrict__ xb) {
    size_t i = (size_t)blockIdx.x * blockDim.x + threadIdx.x;
    float4 a = x[2 * i];
    float4 b = x[2 * i + 1];
    u16x8 o;
    o[0] = f2h(a.x); o[1] = f2h(a.y); o[2] = f2h(a.z); o[3] = f2h(a.w);
    o[4] = f2h(b.x); o[5] = f2h(b.y); o[6] = f2h(b.z); o[7] = f2h(b.w);
    *(u16x8*)&xb[i * 8] = o;
}

// ---------------- prep: weight norm, all 5 layers in 2 launches ----------------
struct WnDesc {
    const float* v; const float* g; u16* wT; float* partial;
    int K; int N; int blk0;
};
struct WnPack { WnDesc d[5]; int nlayer; };

__global__ void wn_partial_all(WnPack p) {
    int b = blockIdx.x;
    int l = 0;
    while (l + 1 < p.nlayer && b >= p.d[l + 1].blk0) l++;
    const WnDesc& d = p.d[l];
    int lb = b - d.blk0;
    int nbx = d.N >> 6;
    int bx = lb % nbx, seg = lb / nbx;

    int lane = threadIdx.x & 63;
    int tr = threadIdx.x >> 6;
    int n = bx * 64 + lane;
    int kseg = d.K >> 3;
    int kbeg = seg * kseg;
    float s = 0.f;
    for (int k = kbeg + tr; k < kbeg + kseg; k += 4) {
        float x = d.v[(size_t)k * d.N + n];
        s += x * x;
    }
    __shared__ float red[4][64];
    red[tr][lane] = s;
    __syncthreads();
    if (tr == 0)
        d.partial[seg * d.N + n] = red[0][lane] + red[1][lane] + red[2][lane] + red[3][lane];
}

__global__ void wn_write_all(WnPack p) {
    int b = blockIdx.x;
    int l = 0;
    while (l + 1 < p.nlayer && b >= p.d[l + 1].blk0) l++;
    const WnDesc& d = p.d[l];
    int lb = b - d.blk0;
    int nbx = d.N >> 6;
    int bx = lb % nbx, seg = lb / nbx;

    int lane = threadIdx.x & 63;
    int tr = threadIdx.x >> 6;
    int n = bx * 64 + lane;
    float s = 0.f;
#pragma unroll
    for (int i = 0; i < 8; i++) s += d.partial[i * d.N + n];
    float sc = d.g[n] / sqrtf(s);

    int kseg = d.K >> 3;
    int kbeg = seg * kseg;
    for (int k = kbeg + tr; k < kbeg + kseg; k += 4)
        d.wT[(size_t)n * d.K + k] = f2h(d.v[(size_t)k * d.N + n] * sc);
}

// ---------------- main GEMM: 128x256 tile, BK=32, 8 waves of 64x64 -------------
// Small-register design: acc 64 + operands 32 + addr ~20 -> <=128 VGPR
// (__launch_bounds__(512,4)) => 2 blocks/CU, 4 waves/SIMD. LDS 48 KB.
// Simple loop; the vmcnt(0) drain is hidden by the co-resident block:
//   stage(nxt,t+1) ; 8 asm ds_reads(cur) ; lgkm(0) ; 16 MFMA ; vmcnt(0) ; bar
// Swizzle: phys slot q = (s + row)&3 (rotation), uniform 8 lanes/bank-quad;
// inverse applied on global source (rule #21), forward on read.
template<int N, int K, bool ACT, bool OUTF32>
__global__ __launch_bounds__(512, 4) void gemm_mb(
    const u16* __restrict__ A, const u16* __restrict__ Bt,
    u16* __restrict__ Ch, float* __restrict__ Cf)
{
    constexpr int M = 65536;
    constexpr int NT = K / 32;          // K-tiles (>=16)
    constexpr int NTN = N / 256;
    constexpr int NWG = (M / 128) * NTN;

    __shared__ u16 sA[2][128 * 32];     // 8 KB each
    __shared__ u16 sB[2][256 * 32];     // 16 KB each

    const int bid = blockIdx.x;
    const int wk = (bid & 7) * (NWG >> 3) + (bid >> 3);   // bijective: NWG%8==0
    const int tm = wk / NTN, tn = wk % NTN;
    const long m0 = (long)tm * 128;
    const int n0 = tn * 256;

    const int tid = threadIdx.x;
    const int lane = tid & 63;
    const int wid = tid >> 6;
    const int wm = (wid >> 2) * 64;     // 2 m-waves
    const int wn = (wid & 3) * 64;      // 4 n-waves

    // ---- staging: 3 gld_lds per tile; inverse-swizzled global k-slot ----
    const int r4 = tid >> 2;                      // staged row 0..127
    const int sG = ((tid & 3) - (r4 & 3)) & 3;    // logical k-slot for phys slot tid&3
    const u16* Ab  = A  + (m0 + r4) * (size_t)K + sG * 8;
    const u16* Bb  = Bt + (size_t)(n0 + r4) * K + sG * 8;
    const u16* Bb2 = Bt + (size_t)(n0 + 128 + r4) * K + sG * 8;
    const int dst8 = tid * 8;

    auto stage = [&](int buf, int t) {
        gld_lds16(Ab + (size_t)t * 32, &sA[buf][dst8]);
        gld_lds16(Bb + (size_t)t * 32, &sB[buf][dst8]);
        gld_lds16(Bb2 + (size_t)t * 32, &sB[buf][4096 + dst8]);
    };

    // ---- fragment read bases (rotation swizzle) ----
    const int lrow = lane & 15;
    const int lq = ((lane >> 4) + (lane & 3)) & 3;   // phys slot for this lane
    const int aoff = (wm + lrow) * 32 + lq * 8;      // u16 units
    const int boff = (wn + lrow) * 32 + lq * 8;

    f32x4 acc[4][4] = {};
    f16x8 a[4], b[4];

    auto BAR = [&]() { __builtin_amdgcn_s_barrier(); };
#define LGKM0 { asm volatile("s_waitcnt lgkmcnt(0)"); __builtin_amdgcn_sched_barrier(0); }
#define VMC0  { asm volatile("s_waitcnt vmcnt(0)");  __builtin_amdgcn_sched_barrier(0); }

    // ---- prologue ----
    stage(0, 0);
    VMC0;
    BAR();

    // ---- main loop ----
    for (int t = 0; t < NT; t++) {
        const int cur = t & 1, nxt = cur ^ 1;
        if (t + 1 < NT) stage(nxt, t + 1);

        const u16* pA = &sA[cur][aoff];
        const u16* pB = &sB[cur][boff];
        a[0] = dsr128o<0>(pA);    a[1] = dsr128o<1024>(pA);
        a[2] = dsr128o<2048>(pA); a[3] = dsr128o<3072>(pA);
        b[0] = dsr128o<0>(pB);    b[1] = dsr128o<1024>(pB);
        b[2] = dsr128o<2048>(pB); b[3] = dsr128o<3072>(pB);
        LGKM0;

        __builtin_amdgcn_s_setprio(1);
#pragma unroll
        for (int i = 0; i < 4; i++)
#pragma unroll
            for (int j = 0; j < 4; j++)
                acc[i][j] = __builtin_amdgcn_mfma_f32_16x16x32_f16(a[i], b[j], acc[i][j], 0, 0, 0);
        __builtin_amdgcn_s_setprio(0);

        if (t + 1 < NT) {
            VMC0;      // forces stage(t+1); drain hidden by co-resident block
            BAR();
        }
    }
#undef LGKM0
#undef VMC0

    // ---- epilogue: C layout col = lane&15, row = (lane>>4)*4 + reg ----
    const long crow0 = m0 + wm + ((lane >> 4) << 2);
    const int ccol0 = n0 + wn + (lane & 15);
#pragma unroll
    for (int fi = 0; fi < 4; fi++) {
#pragma unroll
        for (int r = 0; r < 4; r++) {
            const size_t rowoff = (size_t)(crow0 + fi * 16 + r) * N;
#pragma unroll
            for (int fj = 0; fj < 4; fj++) {
                float v = acc[fi][fj][r];
                if (ACT) v = fmaxf(v, 0.f) + __logf(1.f + __expf(-fabsf(v)));
                if (OUTF32) Cf[rowoff + ccol0 + fj * 16] = v;
                else        Ch[rowoff + ccol0 + fj * 16] = f2h(v);
            }
        }
    }
}

// ---------------- launch ----------------
extern "C" void kernel_launch(void* const* d_in, const int* in_sizes, int n_in,
                              void* d_out, int out_size, void* d_ws, size_t ws_size,
                              hipStream_t stream) {
    const float* x  = (const float*)d_in[0];
    const float* v1 = (const float*)d_in[1];
    const float* g1 = (const float*)d_in[2];
    const float* v2 = (const float*)d_in[3];
    const float* g2 = (const float*)d_in[4];
    const float* v3 = (const float*)d_in[5];
    const float* g3 = (const float*)d_in[6];
    const float* v4 = (const float*)d_in[7];
    const float* g4 = (const float*)d_in[8];
    const float* v5 = (const float*)d_in[9];
    const float* g5 = (const float*)d_in[10];
    float* out = (float*)d_out;

    const int M = 65536;
    char* ws = (char*)d_ws;
    u16* bufA = (u16*)(ws);                          // 128 MB
    u16* bufB = (u16*)(ws + 0x8000000ULL);           // 128 MB
    u16* w1T  = (u16*)(ws + 0x10000000ULL);
    u16* w2T  = w1T + 1024 * 512;
    u16* w3T  = w2T + 1024 * 1024;
    u16* w4T  = w3T + 1024 * 1024;
    u16* w5T  = w4T + 1024 * 1024;
    float* part = (float*)(ws + 0x10800000ULL);      // 5 x 8 x 1024 f32

    cvt_x_kernel<<<(M * 512) / (256 * 8), 256, 0, stream>>>((const float4*)x, bufB);

    WnPack pk;
    int cum = 0;
    auto mk = [&](int i, const float* v, const float* g, u16* wT, int K, int N) {
        pk.d[i] = WnDesc{v, g, wT, part + i * 8 * 1024, K, N, cum};
        cum += (N / 64) * 8;
    };
    mk(0, v1, g1, w1T, 512, 1024);
    mk(1, v2, g2, w2T, 1024, 1024);
    mk(2, v3, g3, w3T, 1024, 1024);
    mk(3, v4, g4, w4T, 1024, 1024);
    mk(4, v5, g5, w5T, 1024, 512);
    pk.nlayer = 5;

    wn_partial_all<<<cum, 256, 0, stream>>>(pk);
    wn_write_all<<<cum, 256, 0, stream>>>(pk);

    gemm_mb<1024, 512,  true,  false><<<2048, 512, 0, stream>>>(bufB, w1T, bufA, nullptr);
    gemm_mb<1024, 1024, true,  false><<<2048, 512, 0, stream>>>(bufA, w2T, bufB, nullptr);
    gemm_mb<1024, 1024, true,  false><<<2048, 512, 0, stream>>>(bufB, w3T, bufA, nullptr);
    gemm_mb<1024, 1024, true,  false><<<2048, 512, 0, stream>>>(bufA, w4T, bufB, nullptr);
    gemm_mb<512,  1024, false, true ><<<1024, 512, 0, stream>>>(bufB, w5T, nullptr, out);

    (void)in_sizes; (void)n_in; (void)out_size; (void)ws_size;
}